// Round 2
// baseline (4842.054 us; speedup 1.0000x reference)
//
#include <hip/hip_runtime.h>
#include <hip/hip_bf16.h>

// Problem constants (from reference)
#define V_SZ 32000
#define D_   768
#define NL_  8
#define DI_  1536      // 2*D
#define DS_  16
#define DC_  4
#define DR_  48
#define B_   2
#define L_   512
#define NTOK 1024      // B*L
#define EPS_ 1e-5f

// ---------------------------------------------------------------- helpers
__device__ __forceinline__ float sigmoidf_(float x) { return 1.f / (1.f + __expf(-x)); }
__device__ __forceinline__ float siluf_(float x)    { return x * sigmoidf_(x); }
__device__ __forceinline__ float softplusf_(float x){ return fmaxf(x, 0.f) + log1pf(__expf(-fabsf(x))); }

__device__ __forceinline__ float block_reduce_sum_256(float v, float* sbuf) {
  int tid = threadIdx.x;
  #pragma unroll
  for (int off = 32; off; off >>= 1) v += __shfl_down(v, off, 64);
  __syncthreads();                       // protect sbuf reuse across calls
  if ((tid & 63) == 0) sbuf[tid >> 6] = v;
  __syncthreads();
  return sbuf[0] + sbuf[1] + sbuf[2] + sbuf[3];
}

// ---------------------------------------------------------------- embedding gather
__global__ __launch_bounds__(192) void embed_kernel(
    const int* __restrict__ ids, const float* __restrict__ emb, float* __restrict__ h) {
  int token = blockIdx.x;
  int v = ids[token];
  float4 val = ((const float4*)(emb + (size_t)v * D_))[threadIdx.x];   // 192*4 = 768
  ((float4*)(h + (size_t)token * D_))[threadIdx.x] = val;
}

// ---------------------------------------------------------------- t-embedding (tiny MLP), grid = B*3
__global__ __launch_bounds__(256) void temb_kernel(
    const float* __restrict__ t, const float* __restrict__ tw1, const float* __restrict__ tb1,
    const float* __restrict__ tw2, const float* __restrict__ tb2, float* __restrict__ temb) {
  __shared__ float a[D_];
  int b = blockIdx.x / 3, chunk = blockIdx.x % 3;
  float tv = t[b];
  for (int i = threadIdx.x; i < D_; i += 256) a[i] = siluf_(tv * tw1[i] + tb1[i]);
  __syncthreads();
  int j = chunk * 256 + threadIdx.x;
  float acc = tb2[j];
  for (int d = 0; d < D_; d++) acc += a[d] * tw2[d * D_ + j];
  temb[b * D_ + j] = acc;
}

// ---------------------------------------------------------------- LayerNorm (+optional temb add)
__global__ __launch_bounds__(256) void ln_kernel(
    const float* __restrict__ hin, const float* __restrict__ temb,
    const float* __restrict__ g, const float* __restrict__ bt, float* __restrict__ out) {
  __shared__ float sbuf[4];
  int token = blockIdx.x, b = token >> 9, tid = threadIdx.x;
  float v[3];
  #pragma unroll
  for (int i = 0; i < 3; i++) {
    int c = tid + i * 256;
    float x = hin[(size_t)token * D_ + c];
    if (temb) x += temb[b * D_ + c];
    v[i] = x;
  }
  float mean = block_reduce_sum_256(v[0] + v[1] + v[2], sbuf) * (1.f / D_);
  float d0 = v[0] - mean, d1 = v[1] - mean, d2 = v[2] - mean;
  float var = block_reduce_sum_256(d0 * d0 + d1 * d1 + d2 * d2, sbuf) * (1.f / D_);
  float r = rsqrtf(var + EPS_);
  #pragma unroll
  for (int i = 0; i < 3; i++) {
    int c = tid + i * 256;
    out[(size_t)token * D_ + c] = (v[i] - mean) * r * g[c] + bt[c];
  }
}

// ---------------------------------------------------------------- generic tiled fp32 GEMM
// C[M,N] = A[M,K] @ B[K,N] + bias[N] (+ res[M,N]).  Requires M%BM==0, N%BN==0, K%BK==0.
template <int BM, int BN, int BK, int TM, int TN>
__global__ __launch_bounds__(256) void gemm_f32(
    int M, int N, int K,
    const float* __restrict__ A, const float* __restrict__ B,
    const float* __restrict__ bias, const float* __restrict__ res, float* __restrict__ C) {
  __shared__ float As[BK][BM];
  __shared__ float Bs[BK][BN];
  const int tid = threadIdx.x;
  const int m0 = blockIdx.x * BM;
  const int n0 = blockIdx.y * BN;
  constexpr int TX = BN / TN;            // 16 for both configs
  const int tx = tid % TX;
  const int ty = tid / TX;
  float acc[TM][TN] = {};

  constexpr int AV = BK / 4;             // float4s per A tile row
  const int ar = tid / AV;
  const int ak = (tid % AV) * 4;
  constexpr int BV = BN / 4;
  const int br = tid / BV;
  const int bn = (tid % BV) * 4;
  const float* Aptr = A + (size_t)(m0 + ar) * K + ak;
  const float* Bptr = B + (size_t)br * N + n0 + bn;

  for (int k0 = 0; k0 < K; k0 += BK) {
    float4 av = *(const float4*)(Aptr + k0);
    float4 bv = *(const float4*)(Bptr + (size_t)k0 * N);
    __syncthreads();                     // previous tile's compute done
    As[ak + 0][ar] = av.x; As[ak + 1][ar] = av.y; As[ak + 2][ar] = av.z; As[ak + 3][ar] = av.w;
    *(float4*)&Bs[br][bn] = bv;
    __syncthreads();
    #pragma unroll
    for (int kk = 0; kk < BK; kk++) {
      float a[TM], bb[TN];
      #pragma unroll
      for (int i = 0; i < TM; i++) a[i] = As[kk][ty * TM + i];
      #pragma unroll
      for (int j = 0; j < TN; j++) bb[j] = Bs[kk][tx * TN + j];
      #pragma unroll
      for (int i = 0; i < TM; i++)
        #pragma unroll
        for (int j = 0; j < TN; j++) acc[i][j] += a[i] * bb[j];
    }
  }
  #pragma unroll
  for (int i = 0; i < TM; i++) {
    int m = m0 + ty * TM + i;
    #pragma unroll
    for (int j = 0; j < TN; j += 4) {
      int n = n0 + tx * TN + j;
      float4 o;
      o.x = acc[i][j + 0]; o.y = acc[i][j + 1]; o.z = acc[i][j + 2]; o.w = acc[i][j + 3];
      if (bias) { o.x += bias[n]; o.y += bias[n + 1]; o.z += bias[n + 2]; o.w += bias[n + 3]; }
      if (res) {
        const float4 rv = *(const float4*)&res[(size_t)m * N + n];
        o.x += rv.x; o.y += rv.y; o.z += rv.z; o.w += rv.w;
      }
      *(float4*)&C[(size_t)m * N + n] = o;
    }
  }
}

// ---------------------------------------------------------------- depthwise causal conv(4) + silu
__global__ __launch_bounds__(256) void conv_silu_kernel(
    const float* __restrict__ xz, const float* __restrict__ cw,
    const float* __restrict__ cb, float* __restrict__ xc) {
  int i = blockIdx.x * 256 + threadIdx.x;     // NTOK*DI total
  int d = i % DI_;
  int tk = i / DI_;
  int t = tk & (L_ - 1);
  float acc = cb[d];
  #pragma unroll
  for (int k = 0; k < DC_; k++) {
    int tt = t - 3 + k;
    if (tt >= 0) acc += xz[(size_t)(tk - 3 + k) * (2 * DI_) + d] * cw[d * DC_ + k];
  }
  xc[i] = siluf_(acc);
}

// ---------------------------------------------------------------- xdbl = xc @ W_x  (N=80, K=1536)
__global__ __launch_bounds__(640) void xdbl_kernel(
    const float* __restrict__ xc, const float* __restrict__ Wx, float* __restrict__ xdbl) {
  __shared__ float As[8][DI_];
  int m0 = blockIdx.x * 8;
  for (int i = threadIdx.x; i < 8 * DI_; i += 640)
    As[i / DI_][i % DI_] = xc[(size_t)(m0 + i / DI_) * DI_ + (i % DI_)];
  __syncthreads();
  int r = threadIdx.x / 80, n = threadIdx.x % 80;   // 640 = 8*80
  float acc = 0.f;
  for (int k = 0; k < DI_; k++) acc += As[r][k] * Wx[k * 80 + n];
  xdbl[(size_t)(m0 + r) * 80 + n] = acc;
}

// ---------------------------------------------------------------- dt = softplus(xdbl[:, :48] @ W_dt + b_dt)
__global__ __launch_bounds__(256) void dt_kernel(
    const float* __restrict__ xdbl, const float* __restrict__ Wdt,
    const float* __restrict__ bdt, float* __restrict__ dt) {
  __shared__ float As[4][DR_];
  int m0 = blockIdx.x * 4;
  for (int i = threadIdx.x; i < 4 * DR_; i += 256)
    As[i / DR_][i % DR_] = xdbl[(size_t)(m0 + i / DR_) * 80 + (i % DR_)];
  __syncthreads();
  for (int j = 0; j < DI_ / 256; j++) {
    int n = j * 256 + threadIdx.x;
    float bv0 = bdt[n];
    float a0 = bv0, a1 = bv0, a2 = bv0, a3 = bv0;
    for (int k = 0; k < DR_; k++) {
      float bv = Wdt[k * DI_ + n];
      a0 += As[0][k] * bv; a1 += As[1][k] * bv; a2 += As[2][k] * bv; a3 += As[3][k] * bv;
    }
    dt[(size_t)(m0 + 0) * DI_ + n] = softplusf_(a0);
    dt[(size_t)(m0 + 1) * DI_ + n] = softplusf_(a1);
    dt[(size_t)(m0 + 2) * DI_ + n] = softplusf_(a2);
    dt[(size_t)(m0 + 3) * DI_ + n] = softplusf_(a3);
  }
}

// ---------------------------------------------------------------- selective scan
// grid = B * (DI/16) = 192 blocks; block = 256 = 16 channels x 16 states
#define LCHUNK 64
__global__ __launch_bounds__(256) void scan_kernel(
    const float* __restrict__ dt,    // (NTOK, DI) softplus'd
    const float* __restrict__ xc,    // (NTOK, DI) conv+silu output
    const float* __restrict__ xdbl,  // (NTOK, 80): B at +48, C at +64
    const float* __restrict__ xz,    // (NTOK, 2*DI): z at +DI
    const float* __restrict__ A_log, // (DI, DS) layer slice
    const float* __restrict__ Dp,    // (DI)
    float* __restrict__ y)           // (NTOK, DI)
{
  __shared__ float dts[LCHUNK][16], xs[LCHUNK][16], zs[LCHUNK][16];
  __shared__ float Bs[LCHUNK][16], Cs[LCHUNK][16], ys[LCHUNK][16];
  int blk = blockIdx.x;
  int b = blk / (DI_ / 16);
  int dbase = (blk % (DI_ / 16)) * 16;
  int tid = threadIdx.x;
  int ch = tid >> 4;     // channel within block
  int st = tid & 15;     // state index
  int d = dbase + ch;
  float Av  = -__expf(A_log[d * DS_ + st]);
  float Dpd = Dp[d];
  float s = 0.f;
  int tok0 = b * L_;
  for (int c0 = 0; c0 < L_; c0 += LCHUNK) {
    #pragma unroll
    for (int rep = 0; rep < LCHUNK / 16; rep++) {
      int tt = rep * 16 + (tid >> 4);
      int cc = tid & 15;
      int tok = tok0 + c0 + tt;
      dts[tt][cc] = dt[(size_t)tok * DI_ + dbase + cc];
      xs [tt][cc] = xc[(size_t)tok * DI_ + dbase + cc];
      zs [tt][cc] = xz[(size_t)tok * (2 * DI_) + DI_ + dbase + cc];
      Bs [tt][cc] = xdbl[(size_t)tok * 80 + 48 + cc];
      Cs [tt][cc] = xdbl[(size_t)tok * 80 + 64 + cc];
    }
    __syncthreads();
    for (int tt = 0; tt < LCHUNK; tt++) {
      float dtv = dts[tt][ch];
      float xv  = xs[tt][ch];
      float e = __expf(dtv * Av);
      s = s * e + dtv * xv * Bs[tt][st];
      float p = s * Cs[tt][st];
      p += __shfl_xor(p, 1, 64);
      p += __shfl_xor(p, 2, 64);
      p += __shfl_xor(p, 4, 64);
      p += __shfl_xor(p, 8, 64);
      if (st == 0) {
        float yv = p + Dpd * xv;
        float zv = zs[tt][ch];
        ys[tt][ch] = yv * siluf_(zv);
      }
    }
    __syncthreads();
    #pragma unroll
    for (int rep = 0; rep < LCHUNK / 16; rep++) {
      int tt = rep * 16 + (tid >> 4);
      int cc = tid & 15;
      int tok = tok0 + c0 + tt;
      y[(size_t)tok * DI_ + dbase + cc] = ys[tt][cc];
    }
    __syncthreads();
  }
}

// ---------------------------------------------------------------- launcher
extern "C" void kernel_launch(void* const* d_in, const int* in_sizes, int n_in,
                              void* d_out, int out_size, void* d_ws, size_t ws_size,
                              hipStream_t stream) {
  const int*   ids     = (const int*)  d_in[0];
  const float* t_norm  = (const float*)d_in[1];
  const float* tok_emb = (const float*)d_in[2];
  const float* tw1     = (const float*)d_in[3];
  const float* tb1     = (const float*)d_in[4];
  const float* tw2     = (const float*)d_in[5];
  const float* tb2     = (const float*)d_in[6];
  const float* ln_g    = (const float*)d_in[7];
  const float* ln_b    = (const float*)d_in[8];
  const float* W_in    = (const float*)d_in[9];
  const float* b_in    = (const float*)d_in[10];
  const float* conv_w  = (const float*)d_in[11];
  const float* conv_b  = (const float*)d_in[12];
  const float* W_x     = (const float*)d_in[13];
  const float* W_dt    = (const float*)d_in[14];
  const float* b_dt    = (const float*)d_in[15];
  const float* A_log   = (const float*)d_in[16];
  const float* D_p     = (const float*)d_in[17];
  const float* W_out   = (const float*)d_in[18];
  const float* b_out   = (const float*)d_in[19];
  const float* fn_g    = (const float*)d_in[20];
  const float* fn_b    = (const float*)d_in[21];
  const float* W_head  = (const float*)d_in[22];
  const float* b_head  = (const float*)d_in[23];

  float* ws = (float*)d_ws;
  float* h    = ws; ws += (size_t)NTOK * D_;
  float* hn   = ws; ws += (size_t)NTOK * D_;
  float* temb = ws; ws += (size_t)B_ * D_;
  float* xz   = ws; ws += (size_t)NTOK * 2 * DI_;
  float* xc   = ws; ws += (size_t)NTOK * DI_;
  float* dtb  = ws; ws += (size_t)NTOK * DI_;
  float* xdbl = ws; ws += (size_t)NTOK * 80;
  float* y    = ws; ws += (size_t)NTOK * DI_;

  embed_kernel<<<NTOK, 192, 0, stream>>>(ids, tok_emb, h);
  temb_kernel<<<B_ * 3, 256, 0, stream>>>(t_norm, tw1, tb1, tw2, tb2, temb);

  for (int l = 0; l < NL_; l++) {
    ln_kernel<<<NTOK, 256, 0, stream>>>(h, temb, ln_g + l * D_, ln_b + l * D_, hn);
    gemm_f32<64, 64, 16, 4, 4><<<dim3(NTOK / 64, (2 * DI_) / 64), 256, 0, stream>>>(
        NTOK, 2 * DI_, D_, hn, W_in + (size_t)l * D_ * 2 * DI_, b_in + (size_t)l * 2 * DI_, nullptr, xz);
    conv_silu_kernel<<<(NTOK * DI_) / 256, 256, 0, stream>>>(
        xz, conv_w + (size_t)l * DI_ * DC_, conv_b + (size_t)l * DI_, xc);
    xdbl_kernel<<<NTOK / 8, 640, 0, stream>>>(xc, W_x + (size_t)l * DI_ * 80, xdbl);
    dt_kernel<<<NTOK / 4, 256, 0, stream>>>(
        xdbl, W_dt + (size_t)l * DR_ * DI_, b_dt + (size_t)l * DI_, dtb);
    scan_kernel<<<B_ * (DI_ / 16), 256, 0, stream>>>(
        dtb, xc, xdbl, xz, A_log + (size_t)l * DI_ * DS_, D_p + (size_t)l * DI_, y);
    // NOTE: residual base is hn (the LN output), per reference:
    //   h = _ln(h + t_emb); h = h + _mamba(h)   ->  h_new = hn + mamba(hn)
    gemm_f32<64, 64, 16, 4, 4><<<dim3(NTOK / 64, D_ / 64), 256, 0, stream>>>(
        NTOK, D_, DI_, y, W_out + (size_t)l * DI_ * D_, b_out + (size_t)l * D_, hn, h);
  }

  ln_kernel<<<NTOK, 256, 0, stream>>>(h, nullptr, fn_g, fn_b, hn);
  gemm_f32<128, 128, 8, 8, 8><<<dim3(NTOK / 128, V_SZ / 128), 256, 0, stream>>>(
      NTOK, V_SZ, D_, hn, W_head, b_head, nullptr, (float*)d_out);
}